// Round 12
// baseline (235.951 us; speedup 1.0000x reference)
//
#include <hip/hip_runtime.h>
#include <hip/hip_bf16.h>

// Problem constants (from reference)
#define B_   4
#define S_   2048
#define DIN  1024
#define DH   1024
#define DOUT 1024

typedef __attribute__((ext_vector_type(8))) __bf16 bf16x8;
typedef __attribute__((ext_vector_type(4))) float floatx4;
typedef unsigned short u16;
typedef unsigned int u32;
typedef unsigned long long u64;
typedef __attribute__((ext_vector_type(8))) u16 u16x8;

__device__ inline u16 f2bf(float f) {
  union { float f; u32 u; } x; x.f = f;
  u32 r = x.u + 0x7fffu + ((x.u >> 16) & 1u);  // RTNE
  return (u16)(r >> 16);
}

#define GLOAD(SRC, DST) __builtin_amdgcn_global_load_lds(                     \
    (const __attribute__((address_space(1))) u32*)(SRC),                      \
    (__attribute__((address_space(3))) u32*)(DST), 16, 0, 0)
#define WAITVM0() asm volatile("s_waitcnt vmcnt(0)" ::: "memory")

// ---------------------------------------------------------------------------
// prep: ONE launch, block-range dispatch with STATIC per-region trip counts
// (R11's version ran at 1.8 TB/s with VGPR=8: runtime if-chain per iteration
// + minimal regalloc = one load in flight, latency-bound.  Fix = region
// resolved per block (uniform), fully-unrolled static loops, 2x float4 load
// + 1x 16B store per iteration -> 8+ loads in flight).
//   [0,1536):    q/k/v cast, 512 blocks each; 8 iters/thread
//   [1536,1664): w0..w3 cast, 32 blocks each; 16 iters/thread
//   [1664,1920): mask -> packed bits (int4 + 4x ballot); 64 iters, unroll 4
//                layout: granule g = 256 ints -> packed[g*4+j] bit l
//                        <-> mask[g*256 + 4l + j]
//   [1920,1932): bias gather into bcat[3][DH]
// ---------------------------------------------------------------------------
__global__ __launch_bounds__(256)
void prep(const float* __restrict__ q, const float* __restrict__ k,
          const float* __restrict__ v, const float* __restrict__ w0,
          const float* __restrict__ w1, const float* __restrict__ w2,
          const float* __restrict__ w3, u16* __restrict__ dst,
          const int* __restrict__ mask, u64* __restrict__ packed,
          const float* __restrict__ b0, const float* __restrict__ b1,
          const float* __restrict__ b2, float* __restrict__ bcat) {
  const long nQ = (long)B_ * S_ * DIN;     // 8,388,608 elems
  const long nW = (long)DH * DIN;          // 1,048,576 elems
  const int b = blockIdx.x;
  const int tid = threadIdx.x;

  if (b < 1536) {
    // q/k/v: 1,048,576 units of 8 floats / 131,072 threads = 8 iterations
    const int r = b >> 9;                          // 0=q 1=k 2=v
    const float* src = (r == 0) ? q : (r == 1) ? k : v;
    u16* d = dst + (long)r * nQ;
    const long gt = (long)(b & 511) * 256 + tid;   // 0..131071
#pragma unroll
    for (int it = 0; it < 8; ++it) {
      const long u = gt + (long)it * 131072;
      float4 v0 = ((const float4*)src)[2 * u];
      float4 v1 = ((const float4*)src)[2 * u + 1];
      u16x8 o;
      o[0] = f2bf(v0.x); o[1] = f2bf(v0.y); o[2] = f2bf(v0.z); o[3] = f2bf(v0.w);
      o[4] = f2bf(v1.x); o[5] = f2bf(v1.y); o[6] = f2bf(v1.z); o[7] = f2bf(v1.w);
      ((u16x8*)d)[u] = o;
    }
  } else if (b < 1664) {
    // weights: 131,072 units of 8 / 8,192 threads = 16 iterations
    const int r = (b - 1536) >> 5;                 // 0..3
    const float* src = (r == 0) ? w0 : (r == 1) ? w1 : (r == 2) ? w2 : w3;
    u16* d = dst + 3 * nQ + (long)r * nW;
    const long gt = (long)((b - 1536) & 31) * 256 + tid;  // 0..8191
#pragma unroll 4
    for (int it = 0; it < 16; ++it) {
      const long u = gt + (long)it * 8192;
      float4 v0 = ((const float4*)src)[2 * u];
      float4 v1 = ((const float4*)src)[2 * u + 1];
      u16x8 o;
      o[0] = f2bf(v0.x); o[1] = f2bf(v0.y); o[2] = f2bf(v0.z); o[3] = f2bf(v0.w);
      o[4] = f2bf(v1.x); o[5] = f2bf(v1.y); o[6] = f2bf(v1.z); o[7] = f2bf(v1.w);
      ((u16x8*)d)[u] = o;
    }
  } else if (b < 1920) {
    // mask: 4,194,304 int4s / 65,536 threads = 64 iterations
    const long gt = (long)(b - 1664) * 256 + tid;  // 0..65535
#pragma unroll 4
    for (int it = 0; it < 64; ++it) {
      const long f = gt + (long)it * 65536;
      int4 m4 = ((const int4*)mask)[f];
      u64 bal0 = __ballot(m4.x != 0);
      u64 bal1 = __ballot(m4.y != 0);
      u64 bal2 = __ballot(m4.z != 0);
      u64 bal3 = __ballot(m4.w != 0);
      if ((tid & 63) == 0) {
        const long g = f >> 6;          // wave-uniform (f base 64-aligned)
        ulonglong2 p01; p01.x = bal0; p01.y = bal1;
        ulonglong2 p23; p23.x = bal2; p23.y = bal3;
        ((ulonglong2*)(packed + g * 4))[0] = p01;
        ((ulonglong2*)(packed + g * 4))[1] = p23;
      }
    }
  } else {
    int i = (b - 1920) * 256 + tid;
    if (i < DH) bcat[i] = b0[i];
    else if (i < 2 * DH) bcat[i] = b1[i - DH];
    else if (i < 3 * DH) bcat[i] = b2[i - 2 * DH];
  }
}

// ---------------------------------------------------------------------------
// bf16 32x32-tile transpose (V -> V^T so PV becomes a B^T GEMM)
// ---------------------------------------------------------------------------
__global__ __launch_bounds__(256)
void transpose_bf16(const u16* __restrict__ in, u16* __restrict__ out) {
  __shared__ u16 t[32][33];
  const int b = blockIdx.z;
  const int r0 = blockIdx.y * 32, c0 = blockIdx.x * 32;
  const int tx = threadIdx.x & 31, ty = threadIdx.x >> 5;  // 32 x 8
  const u16* ib = in + (long)b * S_ * DH;
  u16* ob = out + (long)b * DH * S_;
#pragma unroll
  for (int i = 0; i < 4; ++i) {
    int r = ty + i * 8;
    t[r][tx] = ib[(long)(r0 + r) * DH + (c0 + tx)];
  }
  __syncthreads();
#pragma unroll
  for (int i = 0; i < 4; ++i) {
    int r = ty + i * 8;
    ob[(long)(c0 + r) * S_ + (r0 + tx)] = t[tx][r];
  }
}

// ---------------------------------------------------------------------------
// gemm97: m97-replica bf16 B^T GEMM.  C[M,N] = A[M,K] @ B[N,K]^T (+epilogue).
//   BM=BN=128, BK=64, 4 waves (2x2; 64x64 per wave), 16x16x32 MFMA.
//   LDS 32 KB SINGLE buffer, XOR-swizzled slots (T2); staging dest LINEAR
//   (rule 21), global src carries the inverse slot permutation.
//   launch_bounds(256,4): 4 blocks/CU resident cover the per-tile drain.
//   EPI_BF16_ROWSCALE computes 1/rowsum from Psum in a tiny prologue.
// ---------------------------------------------------------------------------
#define EPI_BF16_BIAS     0   // C u16 : v + bias[bz*sBias+col]
#define EPI_BF16_ROWSCALE 1   // C u16 : v / rowsum  (rowsum from Psum[.,16])
#define EPI_F32_BIAS      2   // C f32 : v + bias[col]

template <int EPI>
__global__ __launch_bounds__(256, 4)
void gemm97(const u16* __restrict__ A, const u16* __restrict__ Bm,
            void* __restrict__ C, const float* __restrict__ bias,
            const float* __restrict__ Psum,
            int M, int N, int K,
            long sA, long sB, long sC, long sBias,
            int nbx, int nby) {
  __shared__ u16 lds_[16384];   // A 8192 u16 | B 8192 u16
  __shared__ float invs_s[(EPI == EPI_BF16_ROWSCALE) ? 128 : 1];

  const int tid = threadIdx.x;
  const int w = tid >> 6, l = tid & 63;
  const int wr = w >> 1, wc = w & 1;
  const int lr = l & 15, q = l >> 4;

  // T1 bijective XCD-chunk swizzle (grid % 8 == 0)
  const int flat = blockIdx.x;
  const int swz = (flat & 7) * ((int)gridDim.x >> 3) + (flat >> 3);
  const int bx = swz % nbx;
  const int rest = swz / nbx;
  const int by = rest % nby;
  const int bz = rest / nby;

  const long arow0 = (long)by * 128;
  const long bcol0 = (long)bx * 128;
  const u16* Ab = A + bz * sA + arow0 * K;
  const u16* Bb = Bm + bz * sB + bcol0 * K;
  const int nt = K >> 6;

  if constexpr (EPI == EPI_BF16_ROWSCALE) {
    // prologue: invs for this block's 128 rows (64B/thread, coalesced)
    if (tid < 128) {
      const float4* p = (const float4*)(Psum + ((long)bz * S_ + arow0 + tid) * 16);
      float4 a = p[0], b = p[1], c = p[2], d = p[3];
      float s = (a.x + a.y + a.z + a.w) + (b.x + b.y + b.z + b.w)
              + (c.x + c.y + c.z + c.w) + (d.x + d.y + d.z + d.w);
      invs_s[tid] = 1.0f / s;
    }
    // visibility guaranteed by the K-loop barriers before epilogue reads
  }

  const int st_r = tid >> 3;                 // 0..31 row within 32-row group
  const int st_ks = (tid & 7) ^ (st_r & 7);  // swizzled global k-slot

  floatx4 acc[4][4] = {};

  for (int t = 0; t < nt; ++t) {
    const long k0 = (long)t << 6;
#pragma unroll
    for (int i = 0; i < 4; ++i)
      GLOAD(Ab + (long)(i * 32 + st_r) * K + k0 + st_ks * 8,
            &lds_[i * 2048 + tid * 8]);
#pragma unroll
    for (int i = 0; i < 4; ++i)
      GLOAD(Bb + (long)(i * 32 + st_r) * K + k0 + st_ks * 8,
            &lds_[8192 + i * 2048 + tid * 8]);
    WAITVM0();         // own stores landed before barrier
    __syncthreads();

    bf16x8 a[4][2], b[4][2];
#pragma unroll
    for (int m = 0; m < 4; ++m)
#pragma unroll
      for (int kk = 0; kk < 2; ++kk) {
        const int r = wr * 64 + m * 16 + lr, s = kk * 4 + q;
        a[m][kk] = *(const bf16x8*)&lds_[r * 64 + ((s ^ (r & 7)) * 8)];
      }
#pragma unroll
    for (int n = 0; n < 4; ++n)
#pragma unroll
      for (int kk = 0; kk < 2; ++kk) {
        const int c = wc * 64 + n * 16 + lr, s = kk * 4 + q;
        b[n][kk] = *(const bf16x8*)&lds_[8192 + c * 64 + ((s ^ (c & 7)) * 8)];
      }
#pragma unroll
    for (int kk = 0; kk < 2; ++kk)
#pragma unroll
      for (int n = 0; n < 4; ++n)
#pragma unroll
        for (int m = 0; m < 4; ++m)
          acc[m][n] = __builtin_amdgcn_mfma_f32_16x16x32_bf16(
              a[m][kk], b[n][kk], acc[m][n], 0, 0, 0);
    __syncthreads();
  }

  // epilogue. C/D layout: col = l&15, row = (l>>4)*4 + reg  [m89]
  const int r4 = q * 4;
#pragma unroll
  for (int mf = 0; mf < 4; ++mf)
#pragma unroll
    for (int nf = 0; nf < 4; ++nf)
#pragma unroll
      for (int r = 0; r < 4; ++r) {
        const long row = arow0 + wr * 64 + mf * 16 + r4 + r;
        const long col = bcol0 + wc * 64 + nf * 16 + lr;
        float v = acc[mf][nf][r];
        if constexpr (EPI == EPI_BF16_BIAS) {
          v += bias[bz * sBias + col];
          ((u16*)C)[bz * sC + row * N + col] = f2bf(v);
        } else if constexpr (EPI == EPI_BF16_ROWSCALE) {
          v *= invs_s[wr * 64 + mf * 16 + r4 + r];
          ((u16*)C)[bz * sC + row * N + col] = f2bf(v);
        } else {  // EPI_F32_BIAS
          v += bias[col];
          ((float*)C)[bz * sC + row * N + col] = v;
        }
      }
}

// ---------------------------------------------------------------------------
// pexp128: m97-structure GEMM (K=1024, nt=16) computing
//   P = exp((Q @ K^T)/32) masked->0 (bf16) + per-block row partial sums.
// K-loop is PURE GEMM; mask bits come from the 2MB packed bitmask
// (ballot-natural layout: packed[g*4+j] bit l <-> int g*256+4l+j),
// coop-loaded (2KB of u32 halves) into dead LDS in the epilogue.
// ---------------------------------------------------------------------------
__global__ __launch_bounds__(256, 4)
void pexp128(const u16* __restrict__ Q, const u16* __restrict__ Kb_,
             u16* __restrict__ P, const u32* __restrict__ packed,
             float* __restrict__ Psum) {
  __shared__ u16 lds_[16384];

  const int tid = threadIdx.x;
  const int w = tid >> 6, l = tid & 63;
  const int wr = w >> 1, wc = w & 1;
  const int lr = l & 15, q = l >> 4;

  // T1 swizzle; grid 1024 = nbx16 x nby16 x z4
  const int flat = blockIdx.x;
  const int swz = (flat & 7) * ((int)gridDim.x >> 3) + (flat >> 3);
  const int bx = swz & 15;
  const int rest = swz >> 4;
  const int by = rest & 15;
  const int bz = rest >> 4;

  const long arow0 = (long)by * 128;
  const long bcol0 = (long)bx * 128;
  const int K = DH;
  const u16* Ab = Q + (long)bz * S_ * DH + arow0 * K;
  const u16* Bb = Kb_ + (long)bz * S_ * DH + bcol0 * K;

  const int st_r = tid >> 3;
  const int st_ks = (tid & 7) ^ (st_r & 7);

  floatx4 acc[4][4] = {};

#pragma unroll 4
  for (int t = 0; t < 16; ++t) {
    const long k0 = (long)t << 6;
#pragma unroll
    for (int i = 0; i < 4; ++i)
      GLOAD(Ab + (long)(i * 32 + st_r) * K + k0 + st_ks * 8,
            &lds_[i * 2048 + tid * 8]);
#pragma unroll
    for (int i = 0; i < 4; ++i)
      GLOAD(Bb + (long)(i * 32 + st_r) * K + k0 + st_ks * 8,
            &lds_[8192 + i * 2048 + tid * 8]);
    WAITVM0();
    __syncthreads();

    bf16x8 a[4][2], b[4][2];
#pragma unroll
    for (int m = 0; m < 4; ++m)
#pragma unroll
      for (int kk = 0; kk < 2; ++kk) {
        const int r = wr * 64 + m * 16 + lr, s = kk * 4 + q;
        a[m][kk] = *(const bf16x8*)&lds_[r * 64 + ((s ^ (r & 7)) * 8)];
      }
#pragma unroll
    for (int n = 0; n < 4; ++n)
#pragma unroll
      for (int kk = 0; kk < 2; ++kk) {
        const int c = wc * 64 + n * 16 + lr, s = kk * 4 + q;
        b[n][kk] = *(const bf16x8*)&lds_[8192 + c * 64 + ((s ^ (c & 7)) * 8)];
      }
#pragma unroll
    for (int kk = 0; kk < 2; ++kk)
#pragma unroll
      for (int n = 0; n < 4; ++n)
#pragma unroll
        for (int m = 0; m < 4; ++m)
          acc[m][n] = __builtin_amdgcn_mfma_f32_16x16x32_bf16(
              a[m][kk], b[n][kk], acc[m][n], 0, 0, 0);
    __syncthreads();
  }

  // ---- epilogue.
  // 1) coop-load packed-mask u32 halves: for row = arow0+lrow, j = 0..3:
  //    pu idx = g*8 + j*2 + (bx&1), g = bz*16384 + row*8 + (bx>>1).
  //    128 rows x 4 u32 = 2KB into dead LDS at byte 16384.
  u32* pw = (u32*)&lds_[8192];    // 512 u32
  {
    const int half = bx & 1;
    const int lrow = tid >> 1;                 // 0..127
    const int j0 = (tid & 1) * 2;              // 0 or 2
    const long g = (long)bz * 16384 + (arow0 + lrow) * 8 + (bx >> 1);
    pw[lrow * 4 + j0]     = packed[g * 8 + j0 * 2 + half];
    pw[lrow * 4 + j0 + 1] = packed[g * 8 + (j0 + 1) * 2 + half];
  }
  __syncthreads();

  // 2) p = bit ? exp(v/32) : 0; bf16 store; row partial sums.
  //    word = pw[lrow*4 + (lr&3)], bit = wc*16 + nf*4 + (lr>>2).
  const int r4 = q * 4;
  float rsum[4][4];
#pragma unroll
  for (int mf = 0; mf < 4; ++mf)
#pragma unroll
    for (int r = 0; r < 4; ++r) rsum[mf][r] = 0.f;

#pragma unroll
  for (int mf = 0; mf < 4; ++mf)
#pragma unroll
    for (int r = 0; r < 4; ++r) {
      const int lrow = wr * 64 + mf * 16 + r4 + r;
      const long row = arow0 + lrow;
      const u32 word = pw[lrow * 4 + (lr & 3)];
#pragma unroll
      for (int nf = 0; nf < 4; ++nf) {
        const int bitpos = wc * 16 + nf * 4 + (lr >> 2);
        const long col = bcol0 + wc * 64 + nf * 16 + lr;
        float p = 0.f;
        if ((word >> bitpos) & 1u) p = __expf(acc[mf][nf][r] * 0.03125f);
        P[(long)bz * S_ * S_ + row * S_ + col] = f2bf(p);
        rsum[mf][r] += p;
      }
    }
  __syncthreads();   // all bit-reads done before Psum scratch reuses LDS

  // 3) reduce over the 16 lr-lanes, then across the 2 wc waves via LDS
  float* sc = (float*)lds_;   // [128 rows][2 wc] f32 at byte 0 (disjoint)
#pragma unroll
  for (int mf = 0; mf < 4; ++mf)
#pragma unroll
    for (int r = 0; r < 4; ++r) {
      float s = rsum[mf][r];
      s += __shfl_xor(s, 1); s += __shfl_xor(s, 2);
      s += __shfl_xor(s, 4); s += __shfl_xor(s, 8);
      if (lr == 0) sc[(wr * 64 + mf * 16 + r4 + r) * 2 + wc] = s;
    }
  __syncthreads();
  if (tid < 128) {
    float tot = sc[tid * 2] + sc[tid * 2 + 1];
    Psum[((long)bz * S_ + arow0 + tid) * 16 + bx] = tot;
  }
}

// ---------------------------------------------------------------------------
extern "C" void kernel_launch(void* const* d_in, const int* in_sizes, int n_in,
                              void* d_out, int out_size, void* d_ws, size_t ws_size,
                              hipStream_t stream) {
  const float* q    = (const float*)d_in[0];
  const float* k    = (const float*)d_in[1];
  const float* v    = (const float*)d_in[2];
  const int*   mask = (const int*)d_in[3];
  const float* Wq   = (const float*)d_in[4];
  const float* bq   = (const float*)d_in[5];
  const float* Wk   = (const float*)d_in[6];
  const float* bk   = (const float*)d_in[7];
  const float* Wv   = (const float*)d_in[8];
  const float* bv   = (const float*)d_in[9];
  const float* Wo   = (const float*)d_in[10];
  const float* bo   = (const float*)d_in[11];

  const long BS = (long)B_ * S_;      // 8192
  const long nQ = BS * DH;            // 8,388,608
  const long nW = (long)DH * DIN;     // 1,048,576
  const long nE = (long)B_ * S_ * S_; // 16,777,216

  char* ws = (char*)d_ws;
  size_t off = 0;
  auto alloc = [&](size_t bytes) {
    void* p = ws + off; off += (bytes + 255) & ~(size_t)255; return p;
  };

  // NOTE: qb..wob must stay CONTIGUOUS in this order (prep assumes it);
  // Qb,Kbf,Vb contiguous (proj z-batch output).
  u16* qb   = (u16*)alloc(nQ * 2);
  u16* kb   = (u16*)alloc(nQ * 2);
  u16* vb   = (u16*)alloc(nQ * 2);
  u16* wqb  = (u16*)alloc(nW * 2);
  u16* wkb  = (u16*)alloc(nW * 2);
  u16* wvb  = (u16*)alloc(nW * 2);
  u16* wob  = (u16*)alloc(nW * 2);
  u16* Qb   = (u16*)alloc(nQ * 2);
  u16* Kbf  = (u16*)alloc(nQ * 2);
  u16* Vb   = (u16*)alloc(nQ * 2);
  u16* VT   = (u16*)alloc(nQ * 2);
  u16* P    = (u16*)alloc(nE * 2);           // exp(e) unnormalized, bf16
  u64* pk   = (u64*)alloc(nE / 8);           // packed mask bits (2MB)
  float* Psum = (float*)alloc(BS * 16 * 4);  // per-block row partials
  float* bcat = (float*)alloc(3 * DH * 4);
  u16* Yb  = vb;  // attention output aliases vb (consumed by proj)
  (void)kb; (void)wkb; (void)wvb;

  // 1. fused prep: casts + mask pack + bias gather (static-trip regions)
  prep<<<dim3(1932), 256, 0, stream>>>(q, k, v, Wq, Wk, Wv, Wo, qb,
                                       mask, pk, bq, bk, bv, bcat);

  // 2. QKV projections, z=3: grid 8x64x3 = 1536
  gemm97<EPI_BF16_BIAS><<<dim3(1536), 256, 0, stream>>>(qb, wqb, Qb, bcat,
      nullptr, (int)BS, DH, DIN, nQ, nW, nQ, DH, 8, 64);

  // 3. V -> V^T per batch
  {
    dim3 g(DH / 32, S_ / 32, B_);
    transpose_bf16<<<g, 256, 0, stream>>>(Vb, VT);
  }

  // 4. P = exp((Q K^T)/32) masked->0 + row partials: grid 16x16x4 = 1024
  pexp128<<<dim3(1024), 256, 0, stream>>>(Qb, Kbf, P, (const u32*)pk, Psum);

  // 5. Y = (P @ V) / rowsum == P[S,S] @ VT[DH,S]^T: grid 8x16x4 = 512
  //    (rowsum reduction folded into the kernel prologue from Psum)
  gemm97<EPI_BF16_ROWSCALE><<<dim3(512), 256, 0, stream>>>(P, VT, Yb,
      nullptr, Psum, S_, DH, S_,
      (long)S_ * S_, (long)DH * S_, (long)S_ * DH, 0, 8, 16);

  // 6. out = Y @ Wo^T + bo -> fp32 d_out: grid 8x64 = 512
  gemm97<EPI_F32_BIAS><<<dim3(512), 256, 0, stream>>>(Yb, wob, d_out, bo,
      nullptr, (int)BS, DOUT, DH, 0, 0, 0, 0, 8, 64);
}

// Round 14
// 235.519 us; speedup vs baseline: 1.0018x; 1.0018x over previous
//
#include <hip/hip_runtime.h>
#include <hip/hip_bf16.h>

// Problem constants (from reference)
#define B_   4
#define S_   2048
#define DIN  1024
#define DH   1024
#define DOUT 1024

typedef __attribute__((ext_vector_type(8))) __bf16 bf16x8;
typedef __attribute__((ext_vector_type(4))) float floatx4;
typedef __attribute__((ext_vector_type(4))) float f32x4;   // native vec for nontemporal
typedef __attribute__((ext_vector_type(4))) u_short u16x4;
typedef unsigned short u16;
typedef unsigned int u32;
typedef unsigned long long u64;

__device__ inline u16 f2bf(float f) {
  union { float f; u32 u; } x; x.f = f;
  u32 r = x.u + 0x7fffu + ((x.u >> 16) & 1u);  // RTNE
  return (u16)(r >> 16);
}

#define GLOAD(SRC, DST) __builtin_amdgcn_global_load_lds(                     \
    (const __attribute__((address_space(1))) u32*)(SRC),                      \
    (__attribute__((address_space(3))) u32*)(DST), 16, 0, 0)
#define WAITVM0() asm volatile("s_waitcnt vmcnt(0)" ::: "memory")

// ---------------------------------------------------------------------------
// cast_all: fp32 -> bf16 for q,k,v,Wq,Wk,Wv,Wo (R9-proven single-shot shape;
// merged multi-region prep variants all tail-stalled at 81-92us).  One
// float4/lane, nontemporal read via native ext_vector_type (R13 fix:
// __builtin_nontemporal_load rejects HIP_vector_type float4).
// ---------------------------------------------------------------------------
__global__ __launch_bounds__(256)
void cast_all(const float* __restrict__ q, const float* __restrict__ k,
              const float* __restrict__ v, const float* __restrict__ w0,
              const float* __restrict__ w1, const float* __restrict__ w2,
              const float* __restrict__ w3, u16* __restrict__ dst) {
  const long nQ = (long)B_ * S_ * DIN;   // 8,388,608
  const long nW = (long)DH * DIN;        // 1,048,576
  long b = blockIdx.x;
  const float* src; long doff;
  if (b < 8192)       { src = q;  doff = 0;            }
  else if (b < 16384) { src = k;  doff = nQ;     b -= 8192;  }
  else if (b < 24576) { src = v;  doff = 2 * nQ; b -= 16384; }
  else if (b < 25600) { src = w0; doff = 3 * nQ; b -= 24576; }
  else if (b < 26624) { src = w1; doff = 3 * nQ + nW;     b -= 25600; }
  else if (b < 27648) { src = w2; doff = 3 * nQ + 2 * nW; b -= 26624; }
  else                { src = w3; doff = 3 * nQ + 3 * nW; b -= 27648; }
  long i = b * 256 + threadIdx.x;        // float4 index within region
  f32x4 vv = __builtin_nontemporal_load(((const f32x4*)src) + i);
  u16x4 o;
  o.x = f2bf(vv.x); o.y = f2bf(vv.y); o.z = f2bf(vv.z); o.w = f2bf(vv.w);
  ((u16x4*)(dst + doff))[i] = o;
}

// ---------------------------------------------------------------------------
// mask_pack: int32 mask -> bitmask (R9-proven shape).  Wave reads 64
// consecutive ints (4B/lane, nontemporal), one __ballot, lane 0 stores u64.
// Layout: packed[i>>6] bit l <-> mask[i base + l]  (no interleaving).
// ---------------------------------------------------------------------------
__global__ __launch_bounds__(256)
void mask_pack(const int* __restrict__ mask, u64* __restrict__ packed) {
  const long i = (long)blockIdx.x * 256 + threadIdx.x;
  const int mk = __builtin_nontemporal_load(mask + i);
  const u64 bal = __ballot(mk != 0);
  if ((threadIdx.x & 63) == 0) packed[i >> 6] = bal;
}

// ---------------------------------------------------------------------------
// bf16 32x32-tile transpose (V -> V^T so PV becomes a B^T GEMM)
// ---------------------------------------------------------------------------
__global__ __launch_bounds__(256)
void transpose_bf16(const u16* __restrict__ in, u16* __restrict__ out) {
  __shared__ u16 t[32][33];
  const int b = blockIdx.z;
  const int r0 = blockIdx.y * 32, c0 = blockIdx.x * 32;
  const int tx = threadIdx.x & 31, ty = threadIdx.x >> 5;  // 32 x 8
  const u16* ib = in + (long)b * S_ * DH;
  u16* ob = out + (long)b * DH * S_;
#pragma unroll
  for (int i = 0; i < 4; ++i) {
    int r = ty + i * 8;
    t[r][tx] = ib[(long)(r0 + r) * DH + (c0 + tx)];
  }
  __syncthreads();
#pragma unroll
  for (int i = 0; i < 4; ++i) {
    int r = ty + i * 8;
    ob[(long)(c0 + r) * S_ + (r0 + tx)] = t[tx][r];
  }
}

// ---------------------------------------------------------------------------
// gemm97: m97-replica bf16 B^T GEMM.  C[M,N] = A[M,K] @ B[N,K]^T (+epilogue).
//   BM=BN=128, BK=64, 4 waves (2x2; 64x64 per wave), 16x16x32 MFMA.
//   LDS 32 KB SINGLE buffer, XOR-swizzled slots (T2); staging dest LINEAR
//   (rule 21), global src carries the inverse slot permutation.
//   launch_bounds(256,4): 4 blocks/CU resident cover the per-tile drain.
//   EPI_BF16_BIAS selects bq/bk/bv by bz (bias gather kernel eliminated).
//   EPI_BF16_ROWSCALE computes 1/rowsum from Psum in a tiny prologue.
// ---------------------------------------------------------------------------
#define EPI_BF16_BIAS     0   // C u16 : v + bias_{bz}[col]
#define EPI_BF16_ROWSCALE 1   // C u16 : v / rowsum  (rowsum from Psum[.,16])
#define EPI_F32_BIAS      2   // C f32 : v + bias0[col]

template <int EPI>
__global__ __launch_bounds__(256, 4)
void gemm97(const u16* __restrict__ A, const u16* __restrict__ Bm,
            void* __restrict__ C,
            const float* __restrict__ bias0, const float* __restrict__ bias1,
            const float* __restrict__ bias2,
            const float* __restrict__ Psum,
            int M, int N, int K,
            long sA, long sB, long sC,
            int nbx, int nby) {
  __shared__ u16 lds_[16384];   // A 8192 u16 | B 8192 u16
  __shared__ float invs_s[(EPI == EPI_BF16_ROWSCALE) ? 128 : 1];

  const int tid = threadIdx.x;
  const int w = tid >> 6, l = tid & 63;
  const int wr = w >> 1, wc = w & 1;
  const int lr = l & 15, q = l >> 4;

  // T1 bijective XCD-chunk swizzle (grid % 8 == 0)
  const int flat = blockIdx.x;
  const int swz = (flat & 7) * ((int)gridDim.x >> 3) + (flat >> 3);
  const int bx = swz % nbx;
  const int rest = swz / nbx;
  const int by = rest % nby;
  const int bz = rest / nby;

  const long arow0 = (long)by * 128;
  const long bcol0 = (long)bx * 128;
  const u16* Ab = A + bz * sA + arow0 * K;
  const u16* Bb = Bm + bz * sB + bcol0 * K;
  const int nt = K >> 6;

  if constexpr (EPI == EPI_BF16_ROWSCALE) {
    // prologue: invs for this block's 128 rows (64B/thread, coalesced)
    if (tid < 128) {
      const float4* p = (const float4*)(Psum + ((long)bz * S_ + arow0 + tid) * 16);
      float4 a = p[0], b = p[1], c = p[2], d = p[3];
      float s = (a.x + a.y + a.z + a.w) + (b.x + b.y + b.z + b.w)
              + (c.x + c.y + c.z + c.w) + (d.x + d.y + d.z + d.w);
      invs_s[tid] = 1.0f / s;
    }
    // visibility guaranteed by the K-loop barriers before epilogue reads
  }

  const int st_r = tid >> 3;                 // 0..31 row within 32-row group
  const int st_ks = (tid & 7) ^ (st_r & 7);  // swizzled global k-slot

  floatx4 acc[4][4] = {};

  for (int t = 0; t < nt; ++t) {
    const long k0 = (long)t << 6;
#pragma unroll
    for (int i = 0; i < 4; ++i)
      GLOAD(Ab + (long)(i * 32 + st_r) * K + k0 + st_ks * 8,
            &lds_[i * 2048 + tid * 8]);
#pragma unroll
    for (int i = 0; i < 4; ++i)
      GLOAD(Bb + (long)(i * 32 + st_r) * K + k0 + st_ks * 8,
            &lds_[8192 + i * 2048 + tid * 8]);
    WAITVM0();         // own stores landed before barrier
    __syncthreads();

    bf16x8 a[4][2], b[4][2];
#pragma unroll
    for (int m = 0; m < 4; ++m)
#pragma unroll
      for (int kk = 0; kk < 2; ++kk) {
        const int r = wr * 64 + m * 16 + lr, s = kk * 4 + q;
        a[m][kk] = *(const bf16x8*)&lds_[r * 64 + ((s ^ (r & 7)) * 8)];
      }
#pragma unroll
    for (int n = 0; n < 4; ++n)
#pragma unroll
      for (int kk = 0; kk < 2; ++kk) {
        const int c = wc * 64 + n * 16 + lr, s = kk * 4 + q;
        b[n][kk] = *(const bf16x8*)&lds_[8192 + c * 64 + ((s ^ (c & 7)) * 8)];
      }
#pragma unroll
    for (int kk = 0; kk < 2; ++kk)
#pragma unroll
      for (int n = 0; n < 4; ++n)
#pragma unroll
        for (int m = 0; m < 4; ++m)
          acc[m][n] = __builtin_amdgcn_mfma_f32_16x16x32_bf16(
              a[m][kk], b[n][kk], acc[m][n], 0, 0, 0);
    __syncthreads();
  }

  // epilogue. C/D layout: col = l&15, row = (l>>4)*4 + reg  [m89]
  const int r4 = q * 4;
  const float* bp = bias0;
  if constexpr (EPI == EPI_BF16_BIAS)
    bp = (bz == 0) ? bias0 : ((bz == 1) ? bias1 : bias2);
#pragma unroll
  for (int mf = 0; mf < 4; ++mf)
#pragma unroll
    for (int nf = 0; nf < 4; ++nf)
#pragma unroll
      for (int r = 0; r < 4; ++r) {
        const long row = arow0 + wr * 64 + mf * 16 + r4 + r;
        const long col = bcol0 + wc * 64 + nf * 16 + lr;
        float v = acc[mf][nf][r];
        if constexpr (EPI == EPI_BF16_BIAS) {
          v += bp[col];
          ((u16*)C)[bz * sC + row * N + col] = f2bf(v);
        } else if constexpr (EPI == EPI_BF16_ROWSCALE) {
          v *= invs_s[wr * 64 + mf * 16 + r4 + r];
          ((u16*)C)[bz * sC + row * N + col] = f2bf(v);
        } else {  // EPI_F32_BIAS
          v += bp[col];
          ((float*)C)[bz * sC + row * N + col] = v;
        }
      }
}

// ---------------------------------------------------------------------------
// pexp128: m97-structure GEMM (K=1024, nt=16) computing
//   P = exp((Q @ K^T)/32) masked->0 (bf16) + per-block row partial sums.
// K-loop is PURE GEMM; mask bits come from the 2MB packed bitmask (R9 layout:
// packed[i>>6] bit l <-> mask int i), coop-loaded (2KB) into dead LDS in the
// epilogue.  R9-verified bit indexing.
// ---------------------------------------------------------------------------
__global__ __launch_bounds__(256, 4)
void pexp128(const u16* __restrict__ Q, const u16* __restrict__ Kb_,
             u16* __restrict__ P, const u32* __restrict__ packed,
             float* __restrict__ Psum) {
  __shared__ u16 lds_[16384];

  const int tid = threadIdx.x;
  const int w = tid >> 6, l = tid & 63;
  const int wr = w >> 1, wc = w & 1;
  const int lr = l & 15, q = l >> 4;

  // T1 swizzle; grid 1024 = nbx16 x nby16 x z4
  const int flat = blockIdx.x;
  const int swz = (flat & 7) * ((int)gridDim.x >> 3) + (flat >> 3);
  const int bx = swz & 15;
  const int rest = swz >> 4;
  const int by = rest & 15;
  const int bz = rest >> 4;

  const long arow0 = (long)by * 128;
  const long bcol0 = (long)bx * 128;
  const int K = DH;
  const u16* Ab = Q + (long)bz * S_ * DH + arow0 * K;
  const u16* Bb = Kb_ + (long)bz * S_ * DH + bcol0 * K;

  const int st_r = tid >> 3;
  const int st_ks = (tid & 7) ^ (st_r & 7);

  floatx4 acc[4][4] = {};

#pragma unroll 4
  for (int t = 0; t < 16; ++t) {
    const long k0 = (long)t << 6;
#pragma unroll
    for (int i = 0; i < 4; ++i)
      GLOAD(Ab + (long)(i * 32 + st_r) * K + k0 + st_ks * 8,
            &lds_[i * 2048 + tid * 8]);
#pragma unroll
    for (int i = 0; i < 4; ++i)
      GLOAD(Bb + (long)(i * 32 + st_r) * K + k0 + st_ks * 8,
            &lds_[8192 + i * 2048 + tid * 8]);
    WAITVM0();
    __syncthreads();

    bf16x8 a[4][2], b[4][2];
#pragma unroll
    for (int m = 0; m < 4; ++m)
#pragma unroll
      for (int kk = 0; kk < 2; ++kk) {
        const int r = wr * 64 + m * 16 + lr, s = kk * 4 + q;
        a[m][kk] = *(const bf16x8*)&lds_[r * 64 + ((s ^ (r & 7)) * 8)];
      }
#pragma unroll
    for (int n = 0; n < 4; ++n)
#pragma unroll
      for (int kk = 0; kk < 2; ++kk) {
        const int c = wc * 64 + n * 16 + lr, s = kk * 4 + q;
        b[n][kk] = *(const bf16x8*)&lds_[8192 + c * 64 + ((s ^ (c & 7)) * 8)];
      }
#pragma unroll
    for (int kk = 0; kk < 2; ++kk)
#pragma unroll
      for (int n = 0; n < 4; ++n)
#pragma unroll
        for (int m = 0; m < 4; ++m)
          acc[m][n] = __builtin_amdgcn_mfma_f32_16x16x32_bf16(
              a[m][kk], b[n][kk], acc[m][n], 0, 0, 0);
    __syncthreads();
  }

  // ---- epilogue.
  // 1) coop-load the block's packed mask words: 128 rows x 4 u32 = 2KB into
  //    dead LDS at byte 16384.. (disjoint from Psum scratch at byte 0).
  u32* pw = (u32*)&lds_[8192];    // 512 u32
  {
    const u32* pg = packed + (long)bz * S_ * (S_ / 32)
                  + arow0 * (S_ / 32) + (bcol0 >> 5);
    const int lrow = tid >> 1;                 // 0..127
    const int j0 = (tid & 1) * 2;              // 0 or 2
    pw[lrow * 4 + j0]     = pg[(long)lrow * (S_ / 32) + j0];
    pw[lrow * 4 + j0 + 1] = pg[(long)lrow * (S_ / 32) + j0 + 1];
  }
  __syncthreads();

  // 2) p = bit ? exp(v/32) : 0; bf16 store; row partial sums.
  //    word = pw[lrow*4 + wc*2 + (nf>>1)], bit = (nf&1)*16 + lr  [R9-verified]
  const int r4 = q * 4;
  float rsum[4][4];
#pragma unroll
  for (int mf = 0; mf < 4; ++mf)
#pragma unroll
    for (int r = 0; r < 4; ++r) rsum[mf][r] = 0.f;

#pragma unroll
  for (int mf = 0; mf < 4; ++mf)
#pragma unroll
    for (int r = 0; r < 4; ++r) {
      const int lrow = wr * 64 + mf * 16 + r4 + r;
      const long row = arow0 + lrow;
#pragma unroll
      for (int nf = 0; nf < 4; ++nf) {
        const u32 word = pw[lrow * 4 + wc * 2 + (nf >> 1)];
        const int bitpos = (nf & 1) * 16 + lr;
        const long col = bcol0 + wc * 64 + nf * 16 + lr;
        float p = 0.f;
        if ((word >> bitpos) & 1u) p = __expf(acc[mf][nf][r] * 0.03125f);
        P[(long)bz * S_ * S_ + row * S_ + col] = f2bf(p);
        rsum[mf][r] += p;
      }
    }
  __syncthreads();   // all bit-reads done before Psum scratch reuses LDS

  // 3) reduce over the 16 lr-lanes, then across the 2 wc waves via LDS
  float* sc = (float*)lds_;   // [128 rows][2 wc] f32 at byte 0 (disjoint)
#pragma unroll
  for (int mf = 0; mf < 4; ++mf)
#pragma unroll
    for (int r = 0; r < 4; ++r) {
      float s = rsum[mf][r];
      s += __shfl_xor(s, 1); s += __shfl_xor(s, 2);
      s += __shfl_xor(s, 4); s += __shfl_xor(s, 8);
      if (lr == 0) sc[(wr * 64 + mf * 16 + r4 + r) * 2 + wc] = s;
    }
  __syncthreads();
  if (tid < 128) {
    float tot = sc[tid * 2] + sc[tid * 2 + 1];
    Psum[((long)bz * S_ + arow0 + tid) * 16 + bx] = tot;
  }
}

// ---------------------------------------------------------------------------
extern "C" void kernel_launch(void* const* d_in, const int* in_sizes, int n_in,
                              void* d_out, int out_size, void* d_ws, size_t ws_size,
                              hipStream_t stream) {
  const float* q    = (const float*)d_in[0];
  const float* k    = (const float*)d_in[1];
  const float* v    = (const float*)d_in[2];
  const int*   mask = (const int*)d_in[3];
  const float* Wq   = (const float*)d_in[4];
  const float* bq   = (const float*)d_in[5];
  const float* Wk   = (const float*)d_in[6];
  const float* bk   = (const float*)d_in[7];
  const float* Wv   = (const float*)d_in[8];
  const float* bv   = (const float*)d_in[9];
  const float* Wo   = (const float*)d_in[10];
  const float* bo   = (const float*)d_in[11];

  const long BS = (long)B_ * S_;      // 8192
  const long nQ = BS * DH;            // 8,388,608
  const long nW = (long)DH * DIN;     // 1,048,576
  const long nE = (long)B_ * S_ * S_; // 16,777,216

  char* ws = (char*)d_ws;
  size_t off = 0;
  auto alloc = [&](size_t bytes) {
    void* p = ws + off; off += (bytes + 255) & ~(size_t)255; return p;
  };

  // NOTE: qb..wob must stay CONTIGUOUS in this order (cast_all assumes it);
  // Qb,Kbf,Vb contiguous (proj z-batch output).
  u16* qb   = (u16*)alloc(nQ * 2);
  u16* kb   = (u16*)alloc(nQ * 2);
  u16* vb   = (u16*)alloc(nQ * 2);
  u16* wqb  = (u16*)alloc(nW * 2);
  u16* wkb  = (u16*)alloc(nW * 2);
  u16* wvb  = (u16*)alloc(nW * 2);
  u16* wob  = (u16*)alloc(nW * 2);
  u16* Qb   = (u16*)alloc(nQ * 2);
  u16* Kbf  = (u16*)alloc(nQ * 2);
  u16* Vb   = (u16*)alloc(nQ * 2);
  u16* VT   = (u16*)alloc(nQ * 2);
  u16* P    = (u16*)alloc(nE * 2);           // exp(e) unnormalized, bf16
  u64* pk   = (u64*)alloc(nE / 8);           // packed mask bits (2MB)
  float* Psum = (float*)alloc(BS * 16 * 4);  // per-block row partials
  u16* Yb  = vb;  // attention output aliases vb (consumed by proj)
  (void)kb; (void)wkb; (void)wvb;

  // 1. casts + mask pack (separate kernels: R9-proven fast shapes)
  cast_all<<<dim3(28672), 256, 0, stream>>>(q, k, v, Wq, Wk, Wv, Wo, qb);
  mask_pack<<<dim3(65536), 256, 0, stream>>>(mask, pk);

  // 2. QKV projections, z=3: grid 8x64x3 = 1536 (bias selected by bz)
  gemm97<EPI_BF16_BIAS><<<dim3(1536), 256, 0, stream>>>(qb, wqb, Qb,
      bq, bk, bv, nullptr, (int)BS, DH, DIN, nQ, nW, nQ, 8, 64);

  // 3. V -> V^T per batch
  {
    dim3 g(DH / 32, S_ / 32, B_);
    transpose_bf16<<<g, 256, 0, stream>>>(Vb, VT);
  }

  // 4. P = exp((Q K^T)/32) masked->0 + row partials: grid 16x16x4 = 1024
  pexp128<<<dim3(1024), 256, 0, stream>>>(Qb, Kbf, P, (const u32*)pk, Psum);

  // 5. Y = (P @ V) / rowsum == P[S,S] @ VT[DH,S]^T: grid 8x16x4 = 512
  //    (rowsum reduction folded into the kernel prologue from Psum)
  gemm97<EPI_BF16_ROWSCALE><<<dim3(512), 256, 0, stream>>>(P, VT, Yb,
      nullptr, nullptr, nullptr, Psum, S_, DH, S_,
      (long)S_ * S_, (long)DH * S_, (long)S_ * DH, 8, 16);

  // 6. out = Y @ Wo^T + bo -> fp32 d_out: grid 8x64 = 512
  gemm97<EPI_F32_BIAS><<<dim3(512), 256, 0, stream>>>(Yb, wob, d_out,
      bo, nullptr, nullptr, nullptr, (int)BS, DOUT, DH, 0, 0, 0, 8, 64);
}